// Round 1
// baseline (171.726 us; speedup 1.0000x reference)
//
#include <hip/hip_runtime.h>
#include <math.h>

#define EPS 1e-6f
#define C_CH 64          // channels (fixed by reference)
#define BPS_A_MAX 128    // blocks per segment, reduction pass
#define BPS_C 256        // blocks per segment, apply pass

// ---------------------------------------------------------------------------
// Pass A: per-block partial sum-of-squares per channel.
// grid = B * BPS_A, block = 256 threads.
// Each block handles a slice of one contiguous segment. Thread t covers
// channels [4*(t&15), 4*(t&15)+3] of row (t>>4) within each 16-row chunk.
// Writes partial[blockIdx.x][64] to workspace (deterministic, no atomics).
// ---------------------------------------------------------------------------
__global__ __launch_bounds__(256) void sumsq_partial(
    const float4* __restrict__ feat,   // [N][16] float4 view of [N][64] f32
    const int* __restrict__ offset,    // [B] cumulative (exclusive end)
    float* __restrict__ partial,       // [B*BPS_A][64]
    int BPS_A)
{
    const int seg  = blockIdx.x / BPS_A;
    const int bip  = blockIdx.x - seg * BPS_A;
    const int start = (seg == 0) ? 0 : offset[seg - 1];
    const int end   = offset[seg];

    const int t    = threadIdx.x;
    const int c4   = t & 15;    // float4 index within row (channels 4*c4..+3)
    const int rsub = t >> 4;    // row within 16-row chunk

    float4 acc = make_float4(0.f, 0.f, 0.f, 0.f);
    const int stride = BPS_A * 16;
    for (int row = start + bip * 16 + rsub; row < end; row += stride) {
        float4 v = feat[row * 16 + c4];
        acc.x = fmaf(v.x, v.x, acc.x);
        acc.y = fmaf(v.y, v.y, acc.y);
        acc.z = fmaf(v.z, v.z, acc.z);
        acc.w = fmaf(v.w, v.w, acc.w);
    }

    __shared__ float lds[16][C_CH];
    lds[rsub][4 * c4 + 0] = acc.x;
    lds[rsub][4 * c4 + 1] = acc.y;
    lds[rsub][4 * c4 + 2] = acc.z;
    lds[rsub][4 * c4 + 3] = acc.w;
    __syncthreads();

    if (t < C_CH) {
        float s = 0.f;
        #pragma unroll
        for (int r = 0; r < 16; ++r) s += lds[r][t];
        partial[(long long)blockIdx.x * C_CH + t] = s;
    }
}

// ---------------------------------------------------------------------------
// Pass B: reduce partials -> response -> per-segment channel mean ->
// mul[b][c] = 1 + gamma[c] * response_norm[b][c].
// One block of B*64 threads; wave w (64 lanes) == segment w, lane == channel.
// ---------------------------------------------------------------------------
__global__ void finalize_kernel(
    const float* __restrict__ partial,  // [B*BPS_A][64]
    const float* __restrict__ gamma,    // [64]
    float* __restrict__ mul,            // [B][64]
    int BPS_A)
{
    const int t   = threadIdx.x;
    const int seg = t >> 6;
    const int c   = t & 63;

    float s = 0.f;
    const float* p = partial + (long long)seg * BPS_A * C_CH + c;
    for (int b = 0; b < BPS_A; ++b) s += p[b * C_CH];

    float resp = sqrtf(s);

    // mean over the 64 channels of this segment (one full wave)
    float tot = resp;
    #pragma unroll
    for (int off = 1; off < 64; off <<= 1) tot += __shfl_xor(tot, off, 64);
    float mean = tot * (1.0f / 64.0f);

    float rn = resp / (mean + EPS);
    mul[t] = 1.0f + gamma[c] * rn;
}

// ---------------------------------------------------------------------------
// Pass C: out = feat * mul[seg] + beta   (float4 in/out, FMA)
// grid = B * BPS_C, block = 256 threads.
// ---------------------------------------------------------------------------
__global__ __launch_bounds__(256) void apply_kernel(
    const float4* __restrict__ feat,
    const int* __restrict__ offset,
    const float* __restrict__ mul,      // [B][64]
    const float4* __restrict__ beta4,   // [16] float4 view of beta[64]
    float4* __restrict__ out)
{
    const int seg = blockIdx.x / BPS_C;
    const int bip = blockIdx.x - seg * BPS_C;
    const int start = (seg == 0) ? 0 : offset[seg - 1];
    const int end   = offset[seg];

    const int t    = threadIdx.x;
    const int c4   = t & 15;
    const int rsub = t >> 4;

    const float4* m4 = (const float4*)(mul + seg * C_CH);
    const float4 m  = m4[c4];
    const float4 bt = beta4[c4];

    const int stride = BPS_C * 16;
    for (int row = start + bip * 16 + rsub; row < end; row += stride) {
        float4 v = feat[row * 16 + c4];
        float4 o;
        o.x = fmaf(v.x, m.x, bt.x);
        o.y = fmaf(v.y, m.y, bt.y);
        o.z = fmaf(v.z, m.z, bt.z);
        o.w = fmaf(v.w, m.w, bt.w);
        out[row * 16 + c4] = o;
    }
}

// ---------------------------------------------------------------------------
extern "C" void kernel_launch(void* const* d_in, const int* in_sizes, int n_in,
                              void* d_out, int out_size, void* d_ws, size_t ws_size,
                              hipStream_t stream)
{
    const float4* feat   = (const float4*)d_in[0];
    const int*    offset = (const int*)d_in[1];
    const float*  gamma  = (const float*)d_in[2];
    const float4* beta4  = (const float4*)d_in[3];
    float4*       out    = (float4*)d_out;

    const int B = in_sizes[1];   // number of segments (8)

    // workspace layout: partial[B*BPS_A][64] floats, then mul[B][64] floats
    int BPS_A = BPS_A_MAX;
    {
        // clamp BPS_A so the workspace fits (safety)
        long long avail = (long long)(ws_size / sizeof(float)) - (long long)B * C_CH;
        if (avail < (long long)B * C_CH) avail = (long long)B * C_CH; // degenerate guard
        long long maxbps = avail / ((long long)B * C_CH);
        if (maxbps < BPS_A) BPS_A = (int)(maxbps > 0 ? maxbps : 1);
    }

    float* partial = (float*)d_ws;                                  // B*BPS_A*64
    float* mul     = partial + (long long)B * BPS_A * C_CH;         // B*64

    sumsq_partial<<<B * BPS_A, 256, 0, stream>>>(feat, offset, partial, BPS_A);
    finalize_kernel<<<1, B * C_CH, 0, stream>>>(partial, gamma, mul, BPS_A);
    apply_kernel<<<B * BPS_C, 256, 0, stream>>>(feat, offset, mul, beta4, out);
}

// Round 3
// 132.902 us; speedup vs baseline: 1.2921x; 1.2921x over previous
//
#include <hip/hip_runtime.h>
#include <math.h>

#define EPS 1e-6f
#define C_CH 64          // channels (fixed by reference)
#define BPS_A 256        // blocks per segment, reduction pass
#define BPS_C 256        // blocks per segment, apply pass

typedef float f32x4 __attribute__((ext_vector_type(4)));  // native vec for builtins

// ---------------------------------------------------------------------------
// Pass A: per-block partial sum-of-squares per channel.
// grid = B * BPS_A, block = 256 threads. Unroll-2 over 16-row chunks.
// Thread t covers float4 (t&15) of row ((t>>4) + 16k) chunks.
// Writes partial[blockIdx.x][64] (deterministic, no atomics).
// Normal (cached) loads on purpose: feat is 256 MB == L3 size, so pass A
// leaves feat resident in Infinity Cache for pass C's re-read.
// ---------------------------------------------------------------------------
__global__ __launch_bounds__(256) void sumsq_partial(
    const float4* __restrict__ feat,   // [N][16] float4 view of [N][64] f32
    const int* __restrict__ offset,    // [B] cumulative (exclusive end)
    float* __restrict__ partial)       // [B*BPS_A][64]
{
    const int seg  = blockIdx.x / BPS_A;
    const int bip  = blockIdx.x - seg * BPS_A;
    const int start = (seg == 0) ? 0 : offset[seg - 1];
    const int end   = offset[seg];

    const int t    = threadIdx.x;
    const int c4   = t & 15;    // float4 index within row
    const int rsub = t >> 4;    // row within 16-row chunk

    float4 a0 = make_float4(0.f, 0.f, 0.f, 0.f);
    float4 a1 = make_float4(0.f, 0.f, 0.f, 0.f);

    const int stride = BPS_A * 32;      // 2 chunks of 16 rows per iter
    for (int row = start + bip * 32 + rsub; row < end; row += stride) {
        float4 v = feat[row * 16 + c4];
        a0.x = fmaf(v.x, v.x, a0.x);
        a0.y = fmaf(v.y, v.y, a0.y);
        a0.z = fmaf(v.z, v.z, a0.z);
        a0.w = fmaf(v.w, v.w, a0.w);
        int row2 = row + 16;
        if (row2 < end) {
            float4 w = feat[row2 * 16 + c4];
            a1.x = fmaf(w.x, w.x, a1.x);
            a1.y = fmaf(w.y, w.y, a1.y);
            a1.z = fmaf(w.z, w.z, a1.z);
            a1.w = fmaf(w.w, w.w, a1.w);
        }
    }
    a0.x += a1.x; a0.y += a1.y; a0.z += a1.z; a0.w += a1.w;

    __shared__ float lds[16][C_CH];
    lds[rsub][4 * c4 + 0] = a0.x;
    lds[rsub][4 * c4 + 1] = a0.y;
    lds[rsub][4 * c4 + 2] = a0.z;
    lds[rsub][4 * c4 + 3] = a0.w;
    __syncthreads();

    if (t < C_CH) {
        float s = 0.f;
        #pragma unroll
        for (int r = 0; r < 16; ++r) s += lds[r][t];
        partial[blockIdx.x * C_CH + t] = s;
    }
}

// ---------------------------------------------------------------------------
// Pass C (fused finalize + apply):
// Prelude: every block redundantly reduces its segment's BPS_A partial rows
// (L2-resident after pass A) -> response -> channel mean ->
// mul[c] = 1 + gamma[c]*rn  in LDS. Deterministic per block.
// Main loop: out = feat * mul + beta, float4, unroll-2,
// NONTEMPORAL stores so `out` doesn't evict feat from Infinity Cache.
// grid = B * BPS_C, block = 256.
// ---------------------------------------------------------------------------
__global__ __launch_bounds__(256) void apply_kernel(
    const float4* __restrict__ feat,
    const int* __restrict__ offset,
    const float* __restrict__ partial,  // [B*BPS_A][64]
    const float* __restrict__ gamma,    // [64]
    const float4* __restrict__ beta4,   // [16] float4 view of beta[64]
    f32x4* __restrict__ out)
{
    const int seg = blockIdx.x / BPS_C;
    const int bip = blockIdx.x - seg * BPS_C;
    const int start = (seg == 0) ? 0 : offset[seg - 1];
    const int end   = offset[seg];

    const int t    = threadIdx.x;
    const int c    = t & 63;     // channel
    const int q    = t >> 6;     // quarter (0..3)

    __shared__ float red[4][C_CH];
    __shared__ float mulsh[C_CH];

    // --- prelude: per-block finalize ---
    {
        float s = 0.f;
        const float* p = partial + (seg * BPS_A) * C_CH + c;
        for (int b = q; b < BPS_A; b += 4) s += p[b * C_CH];
        red[q][c] = s;
        __syncthreads();
        if (t < C_CH) {
            float tot  = red[0][c] + red[1][c] + red[2][c] + red[3][c];
            float resp = sqrtf(tot);
            float m = resp;
            #pragma unroll
            for (int off = 1; off < 64; off <<= 1) m += __shfl_xor(m, off, 64);
            float mean = m * (1.0f / 64.0f);
            float rn   = resp / (mean + EPS);
            mulsh[c] = 1.0f + gamma[c] * rn;
        }
        __syncthreads();
    }

    const int c4 = t & 15;
    const int rsub = t >> 4;
    const float4 mm = ((const float4*)mulsh)[c4];
    const float4 bt = beta4[c4];

    const int stride = BPS_C * 32;
    for (int row = start + bip * 32 + rsub; row < end; row += stride) {
        float4 v = feat[row * 16 + c4];
        f32x4 o;
        o.x = fmaf(v.x, mm.x, bt.x);
        o.y = fmaf(v.y, mm.y, bt.y);
        o.z = fmaf(v.z, mm.z, bt.z);
        o.w = fmaf(v.w, mm.w, bt.w);
        __builtin_nontemporal_store(o, &out[row * 16 + c4]);
        int row2 = row + 16;
        if (row2 < end) {
            float4 w = feat[row2 * 16 + c4];
            f32x4 o2;
            o2.x = fmaf(w.x, mm.x, bt.x);
            o2.y = fmaf(w.y, mm.y, bt.y);
            o2.z = fmaf(w.z, mm.z, bt.z);
            o2.w = fmaf(w.w, mm.w, bt.w);
            __builtin_nontemporal_store(o2, &out[row2 * 16 + c4]);
        }
    }
}

// ---------------------------------------------------------------------------
extern "C" void kernel_launch(void* const* d_in, const int* in_sizes, int n_in,
                              void* d_out, int out_size, void* d_ws, size_t ws_size,
                              hipStream_t stream)
{
    const float4* feat   = (const float4*)d_in[0];
    const int*    offset = (const int*)d_in[1];
    const float*  gamma  = (const float*)d_in[2];
    const float4* beta4  = (const float4*)d_in[3];
    f32x4*        out    = (f32x4*)d_out;

    const int B = in_sizes[1];   // number of segments (8)

    float* partial = (float*)d_ws;   // B*BPS_A*64 floats = 512 KB for B=8

    sumsq_partial<<<B * BPS_A, 256, 0, stream>>>(feat, offset, partial);
    apply_kernel<<<B * BPS_C, 256, 0, stream>>>(feat, offset, partial,
                                                gamma, beta4, (f32x4*)out);
}